// Round 3
// baseline (14.162 us; speedup 1.0000x reference)
//
#include <hip/hip_runtime.h>

// out[b,f,o,r] = log( sum_cin softmax(logits)[o,cin,ki,kj,r] * exp(ll[b,f,cin,r]) )
// ki=(f>>5)&3, kj=f&3. B=128, F=1024, CIN=16, COUT=16, K=4, R=2.
//
// v4: in-block software pipeline over the 4 b-slabs. 4 independent LDS E
// buffers -> write-once/read-after, so each slab needs only ONE raw
// s_barrier preceded by lgkmcnt(0) (NOT __syncthreads: hipcc drains
// vmcnt(0) there, which would serialize the prefetched slab loads).
// Slab j+2's global loads are issued during slab j's stage; weights live
// in 128 VGPRs (read once from LDS, amortized over 4 slabs). Stores
// interleave per slab. Memory floor = 33.5 MB / 6.4 TB/s ~= 5.2 us.

#define WSTRIDE 520  // 512+8: kkloc bank offs 8, q offs 4 -> broadcast/2-way max
#define ESTRIDE 36   // 32+4
#define ESLAB (64 * ESTRIDE)

#define EXP4(v) make_float4(__expf(v.x), __expf(v.y), __expf(v.z), __expf(v.w))

__global__ __launch_bounds__(256, 2) void sumconv_fused(
    const float* __restrict__ ll, const float* __restrict__ logits,
    float* __restrict__ out) {
  __shared__ float sw[8 * WSTRIDE + 4 * ESLAB];  // 4160+9216 floats = 53,504 B
  float* __restrict__ swW = sw;
  float* __restrict__ swE = sw + 8 * WSTRIDE;

  const int tid = threadIdx.x;
  const int blk = blockIdx.x;
  const int f0 = (blk & 15) * 64;
  const int b0 = (blk >> 4) * 4;
  const int kkbase = ((f0 >> 5) & 3) * 4;  // in {0, 8}

  // ---- issue slab 0,1 loads immediately (in flight during softmax) ----
  const float4* __restrict__ s0 = (const float4*)(ll + ((size_t)(b0 + 0) * 1024 + f0) * 32);
  const float4* __restrict__ s1 = (const float4*)(ll + ((size_t)(b0 + 1) * 1024 + f0) * 32);
  const float4* __restrict__ s2 = (const float4*)(ll + ((size_t)(b0 + 2) * 1024 + f0) * 32);
  const float4* __restrict__ s3 = (const float4*)(ll + ((size_t)(b0 + 3) * 1024 + f0) * 32);
  float4 L0a = s0[tid], L0b = s0[tid + 256];
  float4 L1a = s1[tid], L1b = s1[tid + 256];
  float4 L2a, L2b, L3a, L3b;

  // ---- softmax of the 8 needed kk slices -> swW (overlaps load latency) ----
  {
    const int r = tid & 1, kkloc = (tid >> 1) & 7, o = tid >> 4;
    const float* __restrict__ lg = logits + o * 512 + (kkbase + kkloc) * 2 + r;
    float v[16];
    float m = -1e30f;
#pragma unroll
    for (int ci = 0; ci < 16; ++ci) {
      v[ci] = lg[ci * 32];
      m = fmaxf(m, v[ci]);
    }
    float sum = 0.f;
#pragma unroll
    for (int ci = 0; ci < 16; ++ci) {
      v[ci] = __expf(v[ci] - m);
      sum += v[ci];
    }
    const float inv = 1.0f / sum;
#pragma unroll
    for (int ci = 0; ci < 16; ++ci)
      swW[kkloc * WSTRIDE + ci * 32 + o * 2 + r] = v[ci] * inv;
  }
  asm volatile("s_waitcnt lgkmcnt(0)" ::: "memory");
  __builtin_amdgcn_s_barrier();

  // ---- weights -> 128 VGPRs (read once, reused by all 4 slabs) ----
  const int row = tid >> 2, q = tid & 3;
  const int f = f0 + row;
  const int kk = (((f >> 5) & 3) << 2) | (f & 3);
  const float* __restrict__ wb = swW + (kk & 7) * WSTRIDE + q * 4;
  float4 W0[16], W1[16];
#pragma unroll
  for (int ci = 0; ci < 16; ++ci) {
    W0[ci] = *(const float4*)(wb + ci * 32);       // o-pair (2q, 2q+1)
    W1[ci] = *(const float4*)(wb + ci * 32 + 16);  // o-pair (2q+8, 2q+9)
  }

#define SLAB_BODY(J, A, B, ISSUE)                                             \
  {                                                                           \
    ISSUE /* prefetch slab J+2 while staging/computing slab J */              \
    float* __restrict__ ew = swE + (J) * ESLAB;                               \
    *(float4*)(ew + (tid >> 3) * ESTRIDE + (tid & 7) * 4) = EXP4(A);          \
    *(float4*)(ew + ((tid >> 3) + 32) * ESTRIDE + (tid & 7) * 4) = EXP4(B);   \
    asm volatile("s_waitcnt lgkmcnt(0)" ::: "memory");                        \
    __builtin_amdgcn_s_barrier();                                             \
    const float* __restrict__ ebr = swE + (J) * ESLAB + row * ESTRIDE;        \
    float Ef[32];                                                             \
    _Pragma("unroll")                                                         \
    for (int k2 = 0; k2 < 8; ++k2)                                            \
      *(float4*)(Ef + 4 * k2) = *(const float4*)(ebr + 4 * k2);               \
    float4* __restrict__ op =                                                 \
        (float4*)(out + ((size_t)(b0 + (J)) * 1024 + f) * 32);                \
    _Pragma("unroll")                                                         \
    for (int oo = 0; oo < 2; ++oo) {                                          \
      float a0 = 0.f, a1 = 0.f, a2 = 0.f, a3 = 0.f;                           \
      _Pragma("unroll")                                                       \
      for (int ci = 0; ci < 16; ++ci) {                                       \
        const float4 w = oo ? W1[ci] : W0[ci];                                \
        a0 = fmaf(w.x, Ef[2 * ci + 0], a0);                                   \
        a1 = fmaf(w.y, Ef[2 * ci + 1], a1);                                   \
        a2 = fmaf(w.z, Ef[2 * ci + 0], a2);                                   \
        a3 = fmaf(w.w, Ef[2 * ci + 1], a3);                                   \
      }                                                                       \
      op[q + 4 * oo] =                                                        \
          make_float4(__logf(a0), __logf(a1), __logf(a2), __logf(a3));        \
    }                                                                         \
  }

  SLAB_BODY(0, L0a, L0b, L2a = s2[tid]; L2b = s2[tid + 256];)
  SLAB_BODY(1, L1a, L1b, L3a = s3[tid]; L3b = s3[tid + 256];)
  SLAB_BODY(2, L2a, L2b, ;)
  SLAB_BODY(3, L3a, L3b, ;)
#undef SLAB_BODY
}

extern "C" void kernel_launch(void* const* d_in, const int* in_sizes, int n_in,
                              void* d_out, int out_size, void* d_ws, size_t ws_size,
                              hipStream_t stream) {
  const float* ll     = (const float*)d_in[0];
  const float* logits = (const float*)d_in[1];
  float* out = (float*)d_out;
  // 131072 rows / 256 rows-per-block = 512 blocks (64 f x 4 b per block)
  sumconv_fused<<<512, 256, 0, stream>>>(ll, logits, out);
}

// Round 4
// 13.606 us; speedup vs baseline: 1.0408x; 1.0408x over previous
//
#include <hip/hip_runtime.h>

// out[b,f,o,r] = log( sum_cin softmax(logits)[o,cin,ki,kj,r] * exp(ll[b,f,cin,r]) )
// ki=(f>>5)&3, kj=f&3. B=128, F=1024, CIN=16, COUT=16, K=4, R=2.
//
// v5: occupancy x2 (16 waves/CU) at v3's low LDS-read count. 2 rows/thread
// (same f, adjacent b => same kk slice; W float4 feeds 8 FMAs), weights from
// LDS per-ci (not register-hoisted) to stay under 128 VGPR, LDS 35 KB ->
// 4 blocks/CU with __launch_bounds__(256,4). One barrier. 16 independent
// acc chains/thread. All LDS patterns broadcast or <=2-way (free, m136).

#define WSTRIDE 520  // 130 float4-groups, odd-ish (mod 8 = 2): verified 2-way max
#define ESTRIDE 36   // 9 float4-groups, odd: staging conflict-free, reads 2-way

#define EXP4(v) make_float4(__expf(v.x), __expf(v.y), __expf(v.z), __expf(v.w))

__global__ __launch_bounds__(256, 4) void sumconv_fused(
    const float* __restrict__ ll, const float* __restrict__ logits,
    float* __restrict__ out) {
  __shared__ float swW[8 * WSTRIDE];    // 16,640 B
  __shared__ float swE[128 * ESTRIDE];  // 18,432 B   (total 35,072 B)

  const int tid = threadIdx.x;
  const int blk = blockIdx.x;
  const int f0 = (blk & 15) * 64;   // f tile [f0, f0+64)
  const int b0 = (blk >> 4) * 2;    // 2 batch slabs
  const int kkbase = ((f0 >> 5) & 3) * 4;  // in {0, 8}; tile needs kk in [kkbase, kkbase+8)

  // ---- issue both slabs' loads first (in flight during softmax) ----
  const float4* __restrict__ s0 = (const float4*)(ll + ((size_t)(b0 + 0) * 1024 + f0) * 32);
  const float4* __restrict__ s1 = (const float4*)(ll + ((size_t)(b0 + 1) * 1024 + f0) * 32);
  const float4 A0 = s0[tid], A1 = s0[tid + 256];
  const float4 B0 = s1[tid], B1 = s1[tid + 256];

  // ---- softmax of the 8 needed kk slices (exactly 1 task/thread) ----
  {
    const int r = tid & 1, kkloc = (tid >> 1) & 7, o = tid >> 4;
    const float* __restrict__ lg = logits + o * 512 + (kkbase + kkloc) * 2 + r;
    float v[16];
    float m = -1e30f;
#pragma unroll
    for (int ci = 0; ci < 16; ++ci) {
      v[ci] = lg[ci * 32];
      m = fmaxf(m, v[ci]);
    }
    float sum = 0.f;
#pragma unroll
    for (int ci = 0; ci < 16; ++ci) {
      v[ci] = __expf(v[ci] - m);
      sum += v[ci];
    }
    const float inv = 1.0f / sum;
#pragma unroll
    for (int ci = 0; ci < 16; ++ci)
      swW[kkloc * WSTRIDE + ci * 32 + o * 2 + r] = v[ci] * inv;
  }

  // ---- stage exp(ll): slab0 -> E-rows 0..63, slab1 -> E-rows 64..127 ----
  {
    const int row = tid >> 3, c4 = (tid & 7) * 4;
    *(float4*)(swE + (row +  0) * ESTRIDE + c4) = EXP4(A0);
    *(float4*)(swE + (row + 32) * ESTRIDE + c4) = EXP4(A1);
    *(float4*)(swE + (row + 64) * ESTRIDE + c4) = EXP4(B0);
    *(float4*)(swE + (row + 96) * ESTRIDE + c4) = EXP4(B1);
  }
  asm volatile("s_waitcnt lgkmcnt(0)" ::: "memory");
  __builtin_amdgcn_s_barrier();

  // ---- main: thread (row, q) -> o in {2q,2q+1,2q+8,2q+9}, rows (b0,f),(b0+1,f) ----
  const int row = tid >> 2, q = tid & 3;
  const int f = f0 + row;
  const int kk = (((f >> 5) & 3) << 2) | (f & 3);
  const float* __restrict__ wb = swW + (kk & 7) * WSTRIDE + q * 4;

  float Ef0[32], Ef1[32];
  {
    const float* __restrict__ e0 = swE + row * ESTRIDE;
    const float* __restrict__ e1 = swE + (64 + row) * ESTRIDE;
#pragma unroll
    for (int k = 0; k < 8; ++k) {
      *(float4*)(Ef0 + 4 * k) = *(const float4*)(e0 + 4 * k);
      *(float4*)(Ef1 + 4 * k) = *(const float4*)(e1 + 4 * k);
    }
  }

  float a[16];  // [oo(2)][slab(2)][4]
#pragma unroll
  for (int t = 0; t < 16; ++t) a[t] = 0.f;
#pragma unroll
  for (int ci = 0; ci < 16; ++ci) {
    const float4 w0 = *(const float4*)(wb + ci * 32);       // o-pair (2q, 2q+1)
    const float4 w1 = *(const float4*)(wb + ci * 32 + 16);  // o-pair (2q+8, 2q+9)
    const float e00 = Ef0[2 * ci], e01 = Ef0[2 * ci + 1];
    const float e10 = Ef1[2 * ci], e11 = Ef1[2 * ci + 1];
    a[0]  = fmaf(w0.x, e00, a[0]);   a[1]  = fmaf(w0.y, e01, a[1]);
    a[2]  = fmaf(w0.z, e00, a[2]);   a[3]  = fmaf(w0.w, e01, a[3]);
    a[4]  = fmaf(w0.x, e10, a[4]);   a[5]  = fmaf(w0.y, e11, a[5]);
    a[6]  = fmaf(w0.z, e10, a[6]);   a[7]  = fmaf(w0.w, e11, a[7]);
    a[8]  = fmaf(w1.x, e00, a[8]);   a[9]  = fmaf(w1.y, e01, a[9]);
    a[10] = fmaf(w1.z, e00, a[10]);  a[11] = fmaf(w1.w, e01, a[11]);
    a[12] = fmaf(w1.x, e10, a[12]);  a[13] = fmaf(w1.y, e11, a[13]);
    a[14] = fmaf(w1.z, e10, a[14]);  a[15] = fmaf(w1.w, e11, a[15]);
  }

  float4* __restrict__ op0 = (float4*)(out + ((size_t)(b0 + 0) * 1024 + f) * 32);
  float4* __restrict__ op1 = (float4*)(out + ((size_t)(b0 + 1) * 1024 + f) * 32);
  op0[q]     = make_float4(__logf(a[0]),  __logf(a[1]),  __logf(a[2]),  __logf(a[3]));
  op1[q]     = make_float4(__logf(a[4]),  __logf(a[5]),  __logf(a[6]),  __logf(a[7]));
  op0[q + 4] = make_float4(__logf(a[8]),  __logf(a[9]),  __logf(a[10]), __logf(a[11]));
  op1[q + 4] = make_float4(__logf(a[12]), __logf(a[13]), __logf(a[14]), __logf(a[15]));
}

extern "C" void kernel_launch(void* const* d_in, const int* in_sizes, int n_in,
                              void* d_out, int out_size, void* d_ws, size_t ws_size,
                              hipStream_t stream) {
  const float* ll     = (const float*)d_in[0];
  const float* logits = (const float*)d_in[1];
  float* out = (float*)d_out;
  // 131072 rows / 128 rows-per-block = 1024 blocks (64 f x 2 b per block)
  sumconv_fused<<<1024, 256, 0, stream>>>(ll, logits, out);
}